// Round 12
// baseline (261.751 us; speedup 1.0000x reference)
//
#include <hip/hip_runtime.h>
#include <cstdint>
#include <cstddef>

// Attention: B=4, S=2048, H=1024 (single "head", d=1024). fp32 I/O buffers.
// Pipeline: cvt x,W* to bf16 (+zero rowsum) ; fused QKV GEMM ;
//           P = exp(Q·Kᵀ/32) bf16 + atomic rowsums ; out = (P·Vtᵀ)/rowsum.
//
// R21: scores/PV on the ORIGINAL single-buf 128² config (R0-measured 56µs
//   each: BK=64, 32KB LDS, lb(256,4) -> 4 blk/CU, max m114 inter-block
//   overlap).  This quadrant was never tested this session (R17 tested
//   dbuf-2blk = 72µs; 256²-drift-1blk = ~66µs).  Epilogue fusion (exp +
//   atomic rowsums / 1/rowsum) unchanged -- R17 proved it correct on this
//   exact gemm_bt skeleton.  QKV stays dbuf lb(256,2) (70-73µs measured).
//   Ledger: R16=237.1, R18=237.9, R20=235.2 (plateau); prediction here
//   215-224.  If scores/PV >= 66µs, R0's 56 doesn't transfer -> R20 final.
//
// ws layout: [0,16M) xb ; [16,22M) Wqkv ; [22M) rowsum (32KB) ;
//   Q @24M ; Kp @40M ; Vt @56M ; P bf16 @72M (32MB, ends 104M).

typedef __bf16 bf16;
typedef __bf16 bf16x8 __attribute__((ext_vector_type(8)));
typedef __bf16 bf16x4 __attribute__((ext_vector_type(4)));
typedef float f32x4 __attribute__((ext_vector_type(4)));

// ---------------------------------------------------------------- cvt ------
// 8 elements per thread.  XO = x octs, WO = per-W octs.
#define XO (8388608 / 8)
#define WO (1048576 / 8)
__global__ __launch_bounds__(256)
void cvt_all(const float* __restrict__ x, const float* __restrict__ Wq,
             const float* __restrict__ Wk, const float* __restrict__ Wv,
             bf16* __restrict__ xb, bf16* __restrict__ Wqkv,
             float* __restrict__ rsum)
{
    const int i = blockIdx.x * 256 + threadIdx.x;
    if (i < 2048) {                       // zero 8192 f32 rowsums (16B each)
        f32x4 zz = {0.f, 0.f, 0.f, 0.f};
        ((f32x4*)rsum)[i] = zz;
    }
    const float* src;
    bf16* dst;
    if (i < XO) {
        src = x + 8 * (size_t)i;
        dst = xb + 8 * (size_t)i;
    } else {
        const int j = i - XO;                 // 0 .. 3*WO-1
        const int w = j / WO;                 // 0..2
        const int off = j - w * WO;
        const float* ws_ = (w == 0) ? Wq : (w == 1) ? Wk : Wv;
        src = ws_ + 8 * (size_t)off;
        dst = Wqkv + 8 * (size_t)j;
    }
    f32x4 v0 = *(const f32x4*)src;
    f32x4 v1 = *(const f32x4*)(src + 4);
    bf16x8 o;
#pragma unroll
    for (int r = 0; r < 4; ++r) { o[r] = (bf16)v0[r]; o[4 + r] = (bf16)v1[r]; }
    *(bf16x8*)dst = o;
}

// ----------------------------------------- 128²/BK=64 GEMM (R0-proven) -----
#define BM1 128
#define BN1 128
#define BK1 64

// Stage one 128x64 bf16 tile (16 KB) global -> LDS via global_load_lds w=16.
// DMA dest linear (wave-uniform base + lane*16, m104); global source chunk
// (p&7)^(row&7) of row p>>3 (swizzle measured conflict-free in R6).
__device__ __forceinline__ void stage_tile(const bf16* __restrict__ g, int ld,
                                           bf16* lds_generic, int tid)
{
    auto lds3 = (__attribute__((address_space(3))) char*)lds_generic;
    const int wave = tid >> 6;
#pragma unroll
    for (int issue = 0; issue < 4; ++issue) {
        const int p   = issue * 256 + tid;
        const int row = p >> 3;
        const int cp  = p & 7;
        const int c   = cp ^ (row & 7);
        const bf16* gp = g + (size_t)row * ld + c * 8;
        const unsigned wave_base = (unsigned)(issue * 4096 + wave * 1024);
        __builtin_amdgcn_global_load_lds(
            (const __attribute__((address_space(1))) void*)gp,
            (__attribute__((address_space(3))) void*)(lds3 + wave_base),
            16, 0, 0);
    }
}

__device__ __forceinline__ bf16x8 read_frag(const bf16* lds, int row, int chunk)
{
    const int cp = chunk ^ (row & 7);
    return *(const bf16x8*)(lds + row * BK1 + cp * 8);
}

// OUTMODE: 4 = fused QKV (col3>>10 selects {Q,K,Vt}; bias0/1/2 = bq/bk/bv)
//          5 = P = exp(acc*alpha) bf16 + atomic rowsums (scores)
//          6 = f32 out scaled by 1/rowsum[row]         (PV)
// DBUF: 1 = double-buffered cross-iter prefetch (lb 256,2 -- 64KB LDS);
//       0 = single-buffer stage->drain->compute (lb 256,4 -- 32KB LDS,
//           4 blk/CU: the m114 inter-block overlap config, R0: 56µs).
template <int OUTMODE, int DBUF>
__global__ __launch_bounds__(256, DBUF ? 2 : 4)
void gemm_bt(const bf16* __restrict__ A, const bf16* __restrict__ Bm,
             const float* __restrict__ bias0, const float* __restrict__ bias1,
             const float* __restrict__ bias2, void* __restrict__ C,
             float* __restrict__ rsum,
             int K, int N, float alpha, long zA, long zB, long zC)
{
    __shared__ alignas(16) bf16 As[DBUF + 1][BM1 * BK1];
    __shared__ alignas(16) bf16 Bs[DBUF + 1][BN1 * BK1];

    const int tid  = threadIdx.x;
    const int lane = tid & 63;
    const int wid  = tid >> 6;
    const int wr   = (wid >> 1) * 64;   // wave row offset in tile
    const int wc   = (wid & 1) * 64;    // wave col offset in tile
    const int quad = lane >> 4;
    const int l16  = lane & 15;

    const int m0 = blockIdx.y * BM1;
    const int n0 = blockIdx.x * BN1;
    const int z  = blockIdx.z;

    const bf16* Ab = A + (size_t)z * zA + (size_t)m0 * K;
    const bf16* Bb = Bm + (size_t)z * zB + (size_t)n0 * K;

    f32x4 acc[4][4] = {};

    if (DBUF) {
        stage_tile(Ab, K, As[0], tid);
        stage_tile(Bb, K, Bs[0], tid);
    }

    const int niter = K / BK1;
    for (int it = 0; it < niter; ++it) {
        int cur;
        if (DBUF) {
            cur = it & 1;
            __syncthreads();   // buf[cur] staged; prior compute reads done
            if (it + 1 < niter) {
                stage_tile(Ab + (it + 1) * BK1, K, As[cur ^ 1], tid);
                stage_tile(Bb + (it + 1) * BK1, K, Bs[cur ^ 1], tid);
            }
        } else {
            cur = 0;
            __syncthreads();   // prior iteration's LDS reads complete
            stage_tile(Ab + it * BK1, K, As[0], tid);
            stage_tile(Bb + it * BK1, K, Bs[0], tid);
            __syncthreads();   // drains vmcnt(0): tiles visible
        }
#pragma unroll
        for (int h = 0; h < 2; ++h) {
            bf16x8 af[4], bfr[4];
#pragma unroll
            for (int i = 0; i < 4; ++i)
                af[i]  = read_frag(As[cur], wr + i * 16 + l16, h * 4 + quad);
#pragma unroll
            for (int j = 0; j < 4; ++j)
                bfr[j] = read_frag(Bs[cur], wc + j * 16 + l16, h * 4 + quad);
#pragma unroll
            for (int i = 0; i < 4; ++i)
#pragma unroll
                for (int j = 0; j < 4; ++j)
                    acc[i][j] = __builtin_amdgcn_mfma_f32_16x16x32_bf16(
                        af[i], bfr[j], acc[i][j], 0, 0, 0);
        }
    }

    // Epilogue. C/D layout (verified m89): col = lane&15, row = quad*4 + reg.
    if constexpr (OUTMODE == 4) {
#pragma unroll
        for (int j = 0; j < 4; ++j) {
            const int col3 = n0 + wc + j * 16 + l16;
#pragma unroll
            for (int i = 0; i < 4; ++i) {
                const int rbase = m0 + wr + i * 16 + quad * 4;
                const int mat = col3 >> 10;           // 0=Q 1=K 2=V
                const int col = col3 & 1023;
                const float* bp = (mat == 0) ? bias0 : (mat == 1) ? bias1 : bias2;
                const float bj = bp[col];
                if (mat < 2) {
                    bf16* Cb = (bf16*)C + (size_t)mat * (8u << 20);
#pragma unroll
                    for (int r = 0; r < 4; ++r)
                        Cb[(size_t)(rbase + r) * 1024 + col] =
                            (bf16)(acc[i][j][r] + bj);
                } else {
                    // Vt[b][col][s] = V[b*2048+s][col]; quad rows are 4
                    // consecutive s -> one 8B same-type vector store.
                    bf16* Cb = (bf16*)C + (size_t)(16u << 20);
                    const int b = rbase >> 11;
                    const int s = rbase & 2047;
                    bf16x4 tmp;
#pragma unroll
                    for (int r = 0; r < 4; ++r) tmp[r] = (bf16)(acc[i][j][r] + bj);
                    *(bf16x4*)(Cb + (((size_t)((b << 10) + col)) << 11) + s) = tmp;
                }
            }
        }
    } else if constexpr (OUTMODE == 5) {
        // P = exp(acc*alpha) bf16 ; per-row sums -> global atomics.
        float psum[4][4];
#pragma unroll
        for (int i = 0; i < 4; ++i)
#pragma unroll
            for (int r = 0; r < 4; ++r) psum[i][r] = 0.f;

        bf16* Pb = (bf16*)C + (size_t)z * zC;
#pragma unroll
        for (int j = 0; j < 4; ++j) {
            const int col3 = n0 + wc + j * 16 + l16;
#pragma unroll
            for (int i = 0; i < 4; ++i) {
                const int rbase = m0 + wr + i * 16 + quad * 4;
#pragma unroll
                for (int r = 0; r < 4; ++r) {
                    const float p = __expf(acc[i][j][r] * alpha);
                    Pb[(size_t)(rbase + r) * N + col3] = (bf16)p;
                    psum[i][r] += p;
                }
            }
        }
        // reduce over the 16-lane col group (bits 0-3 of lane).
#pragma unroll
        for (int i = 0; i < 4; ++i)
#pragma unroll
            for (int r = 0; r < 4; ++r) {
#pragma unroll
                for (int o = 1; o < 16; o <<= 1)
                    psum[i][r] += __shfl_xor(psum[i][r], o, 64);
            }
        if (l16 == 0) {
            float* rs = rsum + (size_t)z * 2048;
#pragma unroll
            for (int i = 0; i < 4; ++i) {
                const int rbase = m0 + wr + i * 16 + quad * 4;
#pragma unroll
                for (int r = 0; r < 4; ++r)
                    atomicAdd(&rs[rbase + r], psum[i][r]);
            }
        }
    } else {
        // OUTMODE == 6: f32 out, scaled by 1/rowsum[row].
        const float* rs = rsum + (size_t)z * 2048;
#pragma unroll
        for (int j = 0; j < 4; ++j) {
            const int col3 = n0 + wc + j * 16 + l16;
#pragma unroll
            for (int i = 0; i < 4; ++i) {
                const int rbase = m0 + wr + i * 16 + quad * 4;
                float* Cf = (float*)C + (size_t)z * zC;
#pragma unroll
                for (int r = 0; r < 4; ++r)
                    Cf[(size_t)(rbase + r) * N + col3] =
                        acc[i][j][r] * (1.0f / rs[rbase + r]);
            }
        }
    }
}

// ------------------------------------------------------------- launch ------
extern "C" void kernel_launch(void* const* d_in, const int* in_sizes, int n_in,
                              void* d_out, int out_size, void* d_ws, size_t ws_size,
                              hipStream_t stream)
{
    constexpr int B = 4, S = 2048, H = 1024;
    const float* x  = (const float*)d_in[0];
    const float* Wq = (const float*)d_in[1];
    const float* bq = (const float*)d_in[2];
    const float* Wk = (const float*)d_in[3];
    const float* bk = (const float*)d_in[4];
    const float* Wv = (const float*)d_in[5];
    const float* bv = (const float*)d_in[6];
    float* out = (float*)d_out;

    char* ws = (char*)d_ws;
    bf16* xb    = (bf16*)ws;                          // 16 MB
    bf16* Wqkv  = (bf16*)(ws + (size_t)(16 << 20));   //  6 MB
    float* rsum = (float*)(ws + (size_t)(22 << 20));  // 32 KB (8192 f32)
    bf16* Q     = (bf16*)(ws + (size_t)(24 << 20));   // 16 MB (Q|Kp|Vt base)
    bf16* Kp    = (bf16*)(ws + (size_t)(40 << 20));   // 16 MB
    bf16* Vt    = (bf16*)(ws + (size_t)(56 << 20));   // 16 MB
    bf16* P     = (bf16*)(ws + (size_t)(72 << 20));   // 32 MB, ends @104 MB

    dim3 blk(256, 1, 1);

    // fp32 -> bf16 conversions + rowsum zeroing, one dispatch
    cvt_all<<<dim3((XO + 3 * WO) / 256), blk, 0, stream>>>(
        x, Wq, Wk, Wv, xb, Wqkv, rsum);

    // Fused QKV projection: M = 8192, N = 3072, K = 1024 -> Q|Kp|Vt
    // grid 24x64 = 1536 = 3 rounds @ 2 blk/CU (dbuf, R16-measured).
    gemm_bt<4, 1><<<dim3(3 * H / BN1, (B * S) / BM1, 1), blk, 0, stream>>>(
        xb, Wqkv, bq, bk, bv, Q, nullptr, H, 3 * H, 1.0f, 0, 0, 0);

    // P = exp(Q·Kᵀ/32) bf16 + atomic rowsums.
    // single-buf 32KB, 4 blk/CU: grid 16x16x4 = 1024 = 1 round @ 4/CU.
    gemm_bt<5, 0><<<dim3(S / BN1, S / BM1, B), blk, 0, stream>>>(
        Q, Kp, nullptr, nullptr, nullptr, P, rsum, H, S, 0.03125f,
        (long)S * H, (long)S * H, (long)S * S);

    // out = (P·Vtᵀ) × 1/rowsum.  single-buf: grid 8x16x4 = 512 blocks.
    gemm_bt<6, 0><<<dim3(H / BN1, S / BM1, B), blk, 0, stream>>>(
        P, Vt, nullptr, nullptr, nullptr, out, rsum, S, H, 1.0f,
        (long)S * S, (long)H * S, (long)S * H);
}